// Round 7
// baseline (210.935 us; speedup 1.0000x reference)
//
#include <hip/hip_runtime.h>
#include <math.h>

#define N_NODES 50000
#define DEG 16
#define IN_F 256
#define NH 4
#define OUT_F 64
#define HF 256          // NH * OUT_F
#define E_EDGES (N_NODES * DEG)
#define NEG_SLOPE 0.2f

typedef float  floatx4 __attribute__((ext_vector_type(4)));
typedef float  floatx2 __attribute__((ext_vector_type(2)));
typedef int    intx4   __attribute__((ext_vector_type(4)));
typedef unsigned int uintx2 __attribute__((ext_vector_type(2)));
typedef short  short8  __attribute__((ext_vector_type(8)));

__device__ __forceinline__ ushort f2bf(float x) {   // RNE fp32->bf16
    unsigned u = __float_as_uint(x);
    u = (u + 0x7FFFu + ((u >> 16) & 1u)) >> 16;
    return (ushort)u;
}
__device__ __forceinline__ float bf2f(ushort b) {
    return __uint_as_float(((unsigned)b) << 16);
}
__device__ __forceinline__ void gld16(const void* g, void* l) {
    __builtin_amdgcn_global_load_lds((const __attribute__((address_space(1))) void*)g,
                                     (__attribute__((address_space(3))) void*)l, 16, 0, 0);
}

#define STAGE_A8(dst, v0, v1) do { short8 a8_;                        \
    a8_[0] = (short)f2bf((v0).x); a8_[1] = (short)f2bf((v0).y);       \
    a8_[2] = (short)f2bf((v0).z); a8_[3] = (short)f2bf((v0).w);       \
    a8_[4] = (short)f2bf((v1).x); a8_[5] = (short)f2bf((v1).y);       \
    a8_[6] = (short)f2bf((v1).z); a8_[7] = (short)f2bf((v1).w);       \
    *(short8*)(dst) = a8_; } while (0)

// ---- W[256,256] fp32 -> Wt[n][k] bf16 (transposed) ----
__global__ __launch_bounds__(256) void cast_wt_kernel(const float* __restrict__ W,
                                                      ushort* __restrict__ Wt) {
    __shared__ float tile[64][65];
    const int bx = blockIdx.x & 3;    // n tile
    const int by = blockIdx.x >> 2;   // k tile
#pragma unroll
    for (int i = 0; i < 16; ++i) {
        int idx = threadIdx.x + 256 * i;
        int r = idx >> 6, c = idx & 63;
        tile[r][c] = W[(by * 64 + r) * 256 + bx * 64 + c];
    }
    __syncthreads();
#pragma unroll
    for (int i = 0; i < 16; ++i) {
        int idx = threadIdx.x + 256 * i;
        int n = idx >> 6, k = idx & 63;
        Wt[(size_t)(bx * 64 + n) * 256 + by * 64 + k] = f2bf(tile[k][n]);
    }
}

// ---- MFMA GEMM, full-N single pass, double-buffered LDS (R3 version) ----
__global__ __launch_bounds__(256) void mfma_gemm_kernel(const float* __restrict__ A,
                                                        const ushort* __restrict__ Bt,
                                                        const float* __restrict__ attn_l,
                                                        const float* __restrict__ attn_r,
                                                        ushort* __restrict__ H,
                                                        float* __restrict__ arow_g,
                                                        float* __restrict__ acol_g,
                                                        int M) {
    __shared__ __align__(16) ushort smem[20480];
    ushort* Ab[2] = { smem,         smem + 10240 };
    ushort* Bb[2] = { smem + 2048,  smem + 12288 };

    const int tid  = threadIdx.x;
    const int w    = tid >> 6;
    const int lane = tid & 63;
    const int wm   = w >> 1, wn = w & 1;
    const int g    = lane >> 4;
    const int r    = lane & 15;

    const int m0 = blockIdx.x * 64;

    const int srow = tid >> 2;
    const int kc8  = (tid & 3) * 8;
    const int gmA  = min(m0 + srow, M - 1);
    const float*  Aptr = A  + (size_t)gmA  * 256 + kc8;
    const ushort* Bptr = Bt + (size_t)srow * 256 + kc8;

    floatx4 acc[2][8];
#pragma unroll
    for (int i = 0; i < 2; ++i)
#pragma unroll
        for (int j = 0; j < 8; ++j) acc[i][j] = (floatx4)(0.f);

    {
        float4 t0 = *(const float4*)(Aptr);
        float4 t1 = *(const float4*)(Aptr + 4);
        STAGE_A8(Ab[0] + tid * 8, t0, t1);
        gld16(Bptr,             Bb[0] +        tid * 8);
        gld16(Bptr +  64 * 256, Bb[0] + 2048 + tid * 8);
        gld16(Bptr + 128 * 256, Bb[0] + 4096 + tid * 8);
        gld16(Bptr + 192 * 256, Bb[0] + 6144 + tid * 8);
    }
    float4 qx[2], qy[2];
    qx[1] = *(const float4*)(Aptr + 32);  qy[1] = *(const float4*)(Aptr + 36);
    qx[0] = *(const float4*)(Aptr + 64);  qy[0] = *(const float4*)(Aptr + 68);
    __syncthreads();

#pragma unroll
    for (int kk = 0; kk < 8; ++kk) {
        ushort* Ac = Ab[kk & 1];
        ushort* Bc = Bb[kk & 1];
        if (kk < 7) {
            const int nb = (kk + 1) & 1;
            STAGE_A8(Ab[nb] + tid * 8, qx[nb], qy[nb]);
            const ushort* bsrc = Bptr + (kk + 1) * 32;
            gld16(bsrc,             Bb[nb] +        tid * 8);
            gld16(bsrc +  64 * 256, Bb[nb] + 2048 + tid * 8);
            gld16(bsrc + 128 * 256, Bb[nb] + 4096 + tid * 8);
            gld16(bsrc + 192 * 256, Bb[nb] + 6144 + tid * 8);
        }
        if (kk < 5) {
            const int lb = (kk + 3) & 1;
            qx[lb] = *(const float4*)(Aptr + (kk + 3) * 32);
            qy[lb] = *(const float4*)(Aptr + (kk + 3) * 32 + 4);
        }

        short8 af[2], bfr[8];
#pragma unroll
        for (int i = 0; i < 2; ++i)
            af[i] = *(const short8*)&Ac[(size_t)(wm * 32 + i * 16 + r) * 32 + g * 8];
#pragma unroll
        for (int j = 0; j < 8; ++j)
            bfr[j] = *(const short8*)&Bc[(size_t)(wn * 128 + j * 16 + r) * 32 + g * 8];
#pragma unroll
        for (int i = 0; i < 2; ++i)
#pragma unroll
            for (int j = 0; j < 8; ++j)
                acc[i][j] = __builtin_amdgcn_mfma_f32_16x16x32_bf16(af[i], bfr[j], acc[i][j], 0, 0, 0);

        __syncthreads();
    }

    float* wreg = (float*)smem + w * 1024;
    const int rr = lane >> 2;
    const int cb = (lane & 3) * 16;

#pragma unroll
    for (int h = 0; h < 2; ++h) {
        const int head = wn * 2 + h;
        float al[16], ar[16];
#pragma unroll
        for (int q = 0; q < 4; ++q) {
            *(float4*)&al[q * 4] = *(const float4*)(attn_l + head * 64 + cb + q * 4);
            *(float4*)&ar[q * 4] = *(const float4*)(attn_r + head * 64 + cb + q * 4);
        }
#pragma unroll
        for (int i = 0; i < 2; ++i) {
#pragma unroll
            for (int j = 0; j < 4; ++j)
#pragma unroll
                for (int reg = 0; reg < 4; ++reg)
                    wreg[(g * 4 + reg) * 64 + j * 16 + r] = acc[i][h * 4 + j][reg];

            float v[16];
#pragma unroll
            for (int q = 0; q < 4; ++q)
                *(float4*)&v[q * 4] = *(const float4*)&wreg[rr * 64 + cb + q * 4];

            float pl = 0.f, pr = 0.f;
#pragma unroll
            for (int k = 0; k < 16; ++k) { pl += v[k] * al[k]; pr += v[k] * ar[k]; }
            pl += __shfl_xor(pl, 1); pl += __shfl_xor(pl, 2);
            pr += __shfl_xor(pr, 1); pr += __shfl_xor(pr, 2);

            const int gm = m0 + wm * 32 + i * 16 + rr;
            if (gm < M) {
                short8 h0, h1;
#pragma unroll
                for (int k = 0; k < 8; ++k) { h0[k] = (short)f2bf(v[k]); h1[k] = (short)f2bf(v[8 + k]); }
                ushort* dst = H + (size_t)gm * 256 + wn * 128 + h * 64 + cb;
                *(short8*)dst       = h0;
                *(short8*)(dst + 8) = h1;
                if ((lane & 3) == 0) {
                    arow_g[gm * NH + head] = pl;
                    acol_g[gm * NH + head] = pr;
                }
            }
        }
    }
}

// ---- alpha precompute: softmax once, bf16 planes alpha[NH][E] ----
// 1 dst per wave; lane = h*16 + e computes score(h,e) exactly as before.
__global__ __launch_bounds__(256) void alpha_kernel(const int* __restrict__ col_ind,
                                                    const float* __restrict__ arow_g,
                                                    const float* __restrict__ acol_g,
                                                    ushort* __restrict__ aplanes) {
    const int wave = threadIdx.x >> 6, lane = threadIdx.x & 63;
    const int d    = blockIdx.x * 4 + wave;
    const int h    = lane >> 4, e = lane & 15;

    int src = col_ind[d * DEG + e];
    src = src < 0 ? 0 : (src >= N_NODES ? N_NODES - 1 : src);

    float s = arow_g[d * NH + h] + acol_g[src * NH + h];
    s = (s >= 0.f) ? s : NEG_SLOPE * s;
    float m = s;
#pragma unroll
    for (int off = 1; off < 16; off <<= 1)
        m = fmaxf(m, __shfl_xor(m, off));
    float ex = __expf(s - m);
    float su = ex;
#pragma unroll
    for (int off = 1; off < 16; off <<= 1)
        su += __shfl_xor(su, off);

    aplanes[(size_t)h * E_EDGES + d * DEG + e] = f2bf(ex / su);
}

// ---- XCD-sliced aggregate: slice s = blockIdx&7 -> XCD s ----
// XCD s only gathers H[:, 32s:32s+32] (3.2 MB, fits its 4 MiB L2).
// No LDS, no softmax, no random aux reads.  Per wave: 16 dsts = 4 quads.
// Lane (dq,e2,q) = (lane>>4, (lane>>2)&3, lane&3): int4 edge load (edges
// e2*4..e2*4+3), 4 in-lane-accumulated 16B gathers, 2-level shfl tree over
// e2, lanes e2==0 write 32B.  Streams (col_ind/alpha) non-temporal so they
// don't evict the H slice; out stores non-temporal.
__global__ __launch_bounds__(256) void agg_slice_kernel(const int* __restrict__ col_ind,
                                                        const ushort* __restrict__ H,
                                                        const ushort* __restrict__ aplanes,
                                                        float* __restrict__ out) {
    const int s    = blockIdx.x & 7;
    const int head = s >> 1;
    const int wave = threadIdx.x >> 6, lane = threadIdx.x & 63;
    const int dbase = (blockIdx.x >> 3) * 64 + wave * 16;
    const int dq = lane >> 4, e2 = (lane >> 2) & 3, q = lane & 3;

    const ushort* Hs = H + s * 32 + q * 8;
    const ushort* ap = aplanes + (size_t)head * E_EDGES;

    // ---- metas for all 4 quads (nt streams) ----
    intx4  srcv[4];
    uintx2 av[4];
#pragma unroll
    for (int u = 0; u < 4; ++u) {
        int d = dbase + u * 4 + dq;
        d = d < N_NODES ? d : N_NODES - 1;
        srcv[u] = __builtin_nontemporal_load((const intx4*)(col_ind + d * DEG + e2 * 4));
        av[u]   = __builtin_nontemporal_load((const uintx2*)(ap + d * DEG + e2 * 4));
    }

    short8 hv[4][4];
#define CLAMP(x) ((x) < 0 ? 0 : ((x) >= N_NODES ? N_NODES - 1 : (x)))
#define ISSUEQ(u) {                                                            \
        hv[u][0] = *(const short8*)(Hs + (size_t)CLAMP(srcv[u].x) * 256);      \
        hv[u][1] = *(const short8*)(Hs + (size_t)CLAMP(srcv[u].y) * 256);      \
        hv[u][2] = *(const short8*)(Hs + (size_t)CLAMP(srcv[u].z) * 256);      \
        hv[u][3] = *(const short8*)(Hs + (size_t)CLAMP(srcv[u].w) * 256); }

#define CONSQ(u) {                                                             \
        const float a0 = bf2f((ushort)(av[u].x & 0xffff));                     \
        const float a1 = bf2f((ushort)(av[u].x >> 16));                        \
        const float a2 = bf2f((ushort)(av[u].y & 0xffff));                     \
        const float a3 = bf2f((ushort)(av[u].y >> 16));                        \
        float acc[8];                                                          \
        _Pragma("unroll") for (int k = 0; k < 8; ++k)                          \
            acc[k] = a0 * bf2f((ushort)hv[u][0][k])                            \
                   + a1 * bf2f((ushort)hv[u][1][k])                            \
                   + a2 * bf2f((ushort)hv[u][2][k])                            \
                   + a3 * bf2f((ushort)hv[u][3][k]);                           \
        _Pragma("unroll") for (int k = 0; k < 8; ++k) {                        \
            acc[k] += __shfl_xor(acc[k], 4);                                   \
            acc[k] += __shfl_xor(acc[k], 8); }                                 \
        const int d = dbase + (u) * 4 + dq;                                    \
        if (e2 == 0 && d < N_NODES) {                                          \
            float* p = out + (size_t)d * 256 + s * 32 + q * 8;                 \
            floatx4 o0 = { acc[0], acc[1], acc[2], acc[3] };                   \
            floatx4 o1 = { acc[4], acc[5], acc[6], acc[7] };                   \
            __builtin_nontemporal_store(o0, (floatx4*)p);                      \
            __builtin_nontemporal_store(o1, (floatx4*)(p + 4));                \
        } }

    // pipeline: issue 0,1 | consume 0, issue 2 | consume 1, issue 3 | consume 2,3
    ISSUEQ(0); ISSUEQ(1);
    CONSQ(0);  ISSUEQ(2);
    CONSQ(1);  ISSUEQ(3);
    CONSQ(2);
    CONSQ(3);
#undef CLAMP
#undef ISSUEQ
#undef CONSQ
}

// ---- fallback (R3 best-known agg): 1 dst/wave, 8-slot LDS gathers ----
__global__ __launch_bounds__(256) void agg_kernel(const int* __restrict__ col_ind,
                                                  const ushort* __restrict__ H,
                                                  const float* __restrict__ arow_g,
                                                  const float* __restrict__ acol_g,
                                                  float* __restrict__ out) {
    __shared__ __align__(16) ushort lds[4][4096];
    const int wave = threadIdx.x >> 6, lane = threadIdx.x & 63;
    const int d0   = blockIdx.x * 4 + wave;
    const int hidx = lane >> 4, e_s = lane & 15;

    int src0 = col_ind[d0 * DEG + e_s];
    src0 = src0 < 0 ? 0 : (src0 >= N_NODES ? N_NODES - 1 : src0);

    const float sc_r0 = arow_g[d0 * NH + hidx];
    const float sc_c0 = acol_g[src0 * NH + hidx];
    __builtin_amdgcn_sched_barrier(0);

    const int fb     = (lane & 31) * 8;
    const int head_a = (lane & 31) >> 3;
    const int half   = lane >> 5;

    ushort* lbase = &lds[wave][0];
#pragma unroll
    for (int t = 0; t < 8; ++t) {
        const int e  = 2 * t + half;
        const int r0 = __shfl(src0, e);
        gld16(H + (size_t)r0 * 256 + fb, lbase + t * 512 + lane * 8);
    }
    __builtin_amdgcn_sched_barrier(0);

    float s0 = sc_r0 + sc_c0;
    s0 = (s0 >= 0.f) ? s0 : NEG_SLOPE * s0;
    float m0 = s0;
#pragma unroll
    for (int off = 1; off < 16; off <<= 1)
        m0 = fmaxf(m0, __shfl_xor(m0, off));
    float ex0 = expf(s0 - m0);
    float su0 = ex0;
#pragma unroll
    for (int off = 1; off < 16; off <<= 1)
        su0 += __shfl_xor(su0, off);
    const float alpha0 = ex0 / su0;

    float a0[8];
#pragma unroll
    for (int t = 0; t < 8; ++t)
        a0[t] = __shfl(alpha0, head_a * 16 + 2 * t + half);

    asm volatile("s_waitcnt vmcnt(0)" ::: "memory");
    __builtin_amdgcn_sched_barrier(0);

    float acc0[8];
#pragma unroll
    for (int k = 0; k < 8; ++k) acc0[k] = 0.f;
#pragma unroll
    for (int t = 0; t < 8; ++t) {
        short8 hv = *(const short8*)(lbase + t * 512 + lane * 8);
#pragma unroll
        for (int k = 0; k < 8; ++k)
            acc0[k] += a0[t] * bf2f((ushort)hv[k]);
    }
#pragma unroll
    for (int k = 0; k < 8; ++k)
        acc0[k] += __shfl_xor(acc0[k], 32);

    const int qb = half * 4;
    *(float4*)(out + (size_t)d0 * 256 + fb + qb) =
        make_float4(acc0[qb], acc0[qb + 1], acc0[qb + 2], acc0[qb + 3]);
}

extern "C" void kernel_launch(void* const* d_in, const int* in_sizes, int n_in,
                              void* d_out, int out_size, void* d_ws, size_t ws_size,
                              hipStream_t stream) {
    const int*   col_ind = (const int*)d_in[1];
    const float* feat    = (const float*)d_in[4];
    const float* W       = (const float*)d_in[5];
    const float* attn_l  = (const float*)d_in[6];
    const float* attn_r  = (const float*)d_in[7];
    float* out = (float*)d_out;

    // ws: Wt 128KB | h_bf 25.6MB | arow 0.8MB | acol 0.8MB | alpha 6.4MB
    ushort* Wt    = (ushort*)d_ws;
    ushort* h_bf  = Wt + 256 * 256;
    float*  arow  = (float*)(h_bf + (size_t)N_NODES * HF);
    float*  acol  = arow + (size_t)N_NODES * NH;
    ushort* aplanes = (ushort*)(acol + (size_t)N_NODES * NH);

    const size_t need_v1 = (256 * 256 + (size_t)N_NODES * HF) * 2
                         + (size_t)N_NODES * NH * 4 * 2;
    const size_t need_v2 = need_v1 + (size_t)NH * E_EDGES * 2;
    if (ws_size < need_v1) return;

    cast_wt_kernel<<<16, 256, 0, stream>>>(W, Wt);

    mfma_gemm_kernel<<<(N_NODES + 63) / 64, 256, 0, stream>>>(feat, Wt, attn_l, attn_r,
                                                              h_bf, arow, acol, N_NODES);

    if (ws_size >= need_v2) {
        alpha_kernel<<<N_NODES / 4, 256, 0, stream>>>(col_ind, arow, acol, aplanes);
        const int dstblocks = (N_NODES + 63) / 64;
        agg_slice_kernel<<<8 * dstblocks, 256, 0, stream>>>(col_ind, h_bf, aplanes, out);
    } else {
        agg_kernel<<<N_NODES / 4, 256, 0, stream>>>(col_ind, h_bf, arow, acol, out);
    }
}